// Round 8
// baseline (79.052 us; speedup 1.0000x reference)
//
#include <hip/hip_runtime.h>
#include <math.h>

#define N    8192
#define TBL  16384           // hash slots = 2x N
#define TBLM 16383
#define D1B  32              // D1: 32 blocks x 256

// Persistent device-global state — NOT in d_ws, so it survives the
// harness's 256 MiB workspace re-poison (the poison forced a dedicated
// zeroing dispatch in R0-R7; each dispatch boundary costs ~6 µs).
// Validity is epoch-tagged: a slot is live iff its hi32 == this
// iteration's epoch E. E = g_ctr/D1B + 1 via one per-block ticket;
// stream serialization makes E uniform per iteration with no handshake,
// and rocprof per-kernel replays stay self-consistent (D2 reads g_cur).
__device__ unsigned long long g_tbl[TBL];   // (E << 32) | (code+1); .bss -> 0
__device__ unsigned long long g_tkey[TBL];  // (E&0x1FFFFF)<<43 | conf30<<13 | (8191-i)
__device__ unsigned int g_ctr;              // monotone ticket counter
__device__ unsigned int g_cur;              // epoch of the latest D1

// f32 hash pipeline — byte-identical math to the verified version (absmax
// 0.0 in R1-R7). pow via 64-lane shfl LUT: (double)(float)lane bit-equals
// (double)i_f for i_f in [0,23] (R5-verified). Field bounds: qx,qy in
// [0,1035] (11 bits), i,j in [0,23] (5 bits); 5|5|11|11 pack is
// lexicographic in (j,i,qy,qx) == reference decimal-code order. Max code
// <= 0xBDE05C0B so code+1 never wraps and 0xFFFFFFFF is a safe sentinel.
__device__ __forceinline__ unsigned int hslot(unsigned int code) {
    return (code * 2654435761u) >> 18;   // top 14 bits -> [0, TBL)
}

// D1: codes + epoch-tagged insert + winner-key max + compact emit.
// 32 blocks x 256 = one thread per element.
__global__ void __launch_bounds__(256)
k_insert(const float4* __restrict__ rects, const float* __restrict__ conf,
         unsigned long long* __restrict__ v64,
         unsigned int* __restrict__ compact) {
    __shared__ unsigned int s_E;
    const int t = threadIdx.x;
    if (t == 0) {
        unsigned int tk = atomicAdd(&g_ctr, 1u);
        unsigned int E  = (tk >> 5) + 1u;       // tk / D1B + 1
        s_E  = E;
        g_cur = E;                               // benign same-value race
    }
    const int lane = t & 63;
    float powL = (float)pow((double)1.2f, (double)(float)lane);  // R5-verified LUT
    __syncthreads();
    const unsigned int E = s_E;

    const int i = blockIdx.x * 256 + t;
    float4 r = rects[i];
    const float LOG_ALPHA = (float)log((double)1.2f);
    const float LOGW0     = (float)log(512.0);
    float i_f = rintf((LOGW0 - (float)log((double)r.z)) / LOG_ALPHA);
    float j_f = rintf((LOGW0 - (float)log((double)r.w)) / LOG_ALPHA);
    float pi  = __shfl(powL, (int)i_f);
    float pj  = __shfl(powL, (int)j_f);
    float qx  = rintf(r.x / (128.0f / pi) - 0.5f);
    float qy  = rintf(r.y / (128.0f / pj) - 0.5f);
    unsigned int code = (unsigned int)qx | ((unsigned int)qy << 11)
                      | ((unsigned int)i_f << 22) | ((unsigned int)j_f << 27);
    unsigned int cb = __float_as_uint(conf[i]);
    v64[i] = ((unsigned long long)code << 32) | cb;

    // epoch-tagged claim: replace stale (old-epoch) content via CAS-loop;
    // advance past other-code current-epoch slots. Claimed set only grows
    // within an epoch -> exactly one claimer per distinct code.
    unsigned long long want = ((unsigned long long)E << 32) | (code + 1u);
    unsigned int h = hslot(code);
    bool claimed = false;
    for (;;) {
        unsigned long long cur = __hip_atomic_load(&g_tbl[h], __ATOMIC_RELAXED,
                                                   __HIP_MEMORY_SCOPE_AGENT);
        if (cur == want) break;                        // my code already claimed
        if ((unsigned int)(cur >> 32) == E) {          // other code, this epoch
            h = (h + 1) & TBLM;
            continue;
        }
        unsigned long long prev = atomicCAS(&g_tbl[h], cur, want);
        if (prev == cur)  { claimed = true; break; }
        if (prev == want) break;                       // same-code racer won
        // else: slot changed under us -> re-inspect same slot
    }
    compact[i] = claimed ? code : 0xFFFFFFFFu;   // dense-ish distinct set + sentinels

    // winner key: epoch-checked software CAS-max of (conf, 8191-i) —
    // max conf, tie -> smaller index == reference argmax order (R4-verified).
    unsigned long long etag = (unsigned long long)(E & 0x1FFFFFu) << 43;
    unsigned long long mine = etag | ((unsigned long long)cb << 13)
                            | (unsigned int)(8191 - i);
    for (;;) {
        unsigned long long cur = __hip_atomic_load(&g_tkey[h], __ATOMIC_RELAXED,
                                                   __HIP_MEMORY_SCOPE_AGENT);
        if ((cur >> 43) == (etag >> 43) && cur >= mine) break;  // in-epoch, already >=
        unsigned long long prev = atomicCAS(&g_tkey[h], cur, mine);
        if (prev == cur) break;
    }
}

// D2: register-tiled rank + scatter + tail-zero (R7-verified structure).
// 256 blocks x 512; block owns 32 i's. rank_i = #{distinct codes < ci}
// (sentinels never count; self not < self). Each group of 128 threads
// streams all 2048 uint4 of compact from global (coalesced, L2-resident)
// and compares vs 8 SGPR-hoisted i-codes — pure VALU. U counted in the
// same pass; out[U..N) zeroed here (winners cover [0,U) exactly).
__global__ void __launch_bounds__(512)
k_rank(const unsigned long long* __restrict__ v64,
       const unsigned int* __restrict__ compact,
       int* __restrict__ out) {
    __shared__ unsigned int s_ci[32];
    __shared__ int s_part[8][32];        // [wave][i_local]
    __shared__ int s_u[2];
    const int t = threadIdx.x;
    const int b = blockIdx.x;
    if (t < 32) s_ci[t] = (unsigned int)(v64[b * 32 + t] >> 32);
    __syncthreads();

    const int g    = t >> 7;             // 4 groups x 128 threads (2 waves)
    const int lt   = t & 127;
    const int wave = t >> 6;             // 0..7; group = wave>>1

    unsigned int ci[8];
    #pragma unroll
    for (int q = 0; q < 8; ++q)
        ci[q] = __builtin_amdgcn_readfirstlane(s_ci[g * 8 + q]);

    int r[8] = {0, 0, 0, 0, 0, 0, 0, 0};
    int u = 0;
    const uint4* c4 = (const uint4*)compact;   // 2048 uint4 = 8192 entries
    #pragma unroll
    for (int k = 0; k < 16; ++k) {
        uint4 e = c4[lt + k * 128];
        u += (int)(e.x != 0xFFFFFFFFu) + (int)(e.y != 0xFFFFFFFFu)
           + (int)(e.z != 0xFFFFFFFFu) + (int)(e.w != 0xFFFFFFFFu);
        #pragma unroll
        for (int q = 0; q < 8; ++q) {
            r[q] += (int)(e.x < ci[q]) + (int)(e.y < ci[q])
                  + (int)(e.z < ci[q]) + (int)(e.w < ci[q]);
        }
    }
    #pragma unroll
    for (int q = 0; q < 8; ++q) {
        r[q] += __shfl_xor(r[q], 1);
        r[q] += __shfl_xor(r[q], 2);
        r[q] += __shfl_xor(r[q], 4);
        r[q] += __shfl_xor(r[q], 8);
        r[q] += __shfl_xor(r[q], 16);
        r[q] += __shfl_xor(r[q], 32);
    }
    u += __shfl_xor(u, 1);  u += __shfl_xor(u, 2);  u += __shfl_xor(u, 4);
    u += __shfl_xor(u, 8);  u += __shfl_xor(u, 16); u += __shfl_xor(u, 32);
    if ((t & 63) == 0) {
        #pragma unroll
        for (int q = 0; q < 8; ++q)
            s_part[wave][(wave >> 1) * 8 + q] = r[q];
        if (wave < 2) s_u[wave] = u;     // group 0's two waves cover all 2048
    }
    __syncthreads();

    if (t < 32) {
        const int U  = s_u[0] + s_u[1];
        const int i  = b * 32 + t;
        const int gg = t >> 3;
        const int rr = s_part[2 * gg][t] + s_part[2 * gg + 1][t];

        unsigned long long vi = v64[i];
        unsigned int cI = (unsigned int)(vi >> 32);
        unsigned int E  = g_cur;
        unsigned long long wantc = ((unsigned long long)E << 32) | (cI + 1u);
        unsigned int h = hslot(cI);
        int steps = 0;
        while (__hip_atomic_load(&g_tbl[h], __ATOMIC_RELAXED,
                                 __HIP_MEMORY_SCOPE_AGENT) != wantc
               && ++steps < TBL)
            h = (h + 1) & TBLM;
        unsigned long long wk = g_tkey[h];
        bool iswin = ((wk >> 43) == (unsigned long long)(E & 0x1FFFFFu))
                  && (((unsigned int)wk & 0x1FFFu) == (unsigned int)(8191 - i));
        if (iswin)
            out[rr] = ((unsigned int)vi == 0u) ? 0 : i;  // all-conf-0 group -> 0
        if (i >= U)
            out[i] = 0;     // reference pads unique with fill -> argmax 0
    }
}

extern "C" void kernel_launch(void* const* d_in, const int* in_sizes, int n_in,
                              void* d_out, int out_size, void* d_ws, size_t ws_size,
                              hipStream_t stream) {
    const float4* rects = (const float4*)d_in[0];   // (8192, 4) f32
    const float*  conf  = (const float*)d_in[1];    // (8192,)  f32
    int* out = (int*)d_out;                         // int32 indices

    char* ws = (char*)d_ws;
    unsigned long long* v64     = (unsigned long long*)ws;        // 64 KiB
    unsigned int*       compact = (unsigned int*)(ws + 65536);    // 32 KiB

    k_insert<<<D1B, 256, 0, stream>>>(rects, conf, v64, compact);
    k_rank  <<<256, 512, 0, stream>>>(v64, compact, out);
}

// Round 10
// 76.073 us; speedup vs baseline: 1.0392x; 1.0392x over previous
//
#include <hip/hip_runtime.h>
#include <math.h>

#define N    8192
#define TBL  16384           // hash slots = 2x N
#define TBLM 16383
#define D1B  32              // D1: 32 blocks x 256

// Persistent device-global state — NOT in d_ws, so it survives the
// harness's workspace re-poison (which forced a dedicated zeroing dispatch
// in R0-R7; each dispatch boundary costs ~6-8 µs).
//
// Epoch scheme (R8, kept): slot live iff hi32(g_tbl[h]) == E, where
// E = g_ctr/D1B + 1 via one ticket per D1 block; stream serialization
// makes E uniform per dispatch and monotone across dispatches.
//
// R8-regression fix (R9): winner key uses HARDWARE atomicMax with the
// epoch embedded in the top bits — E<<43 | conf30<<13 | (8191-i).
// Monotone E means current-epoch keys numerically supersede all stale
// content: no zeroing, no software CAS-max loop (R8's D1 serializer).
__device__ unsigned long long g_tbl[TBL];   // (E << 32) | (code+1); .bss -> 0
__device__ unsigned long long g_tkey[TBL];  // E<<43 | conf30<<13 | (8191-i)
__device__ unsigned int g_ctr;              // monotone ticket counter
__device__ unsigned int g_cur;              // epoch of the latest D1

// f32 hash pipeline — byte-identical math to the verified version (absmax
// 0.0 in R1-R8). pow via 64-lane shfl LUT: (double)(float)lane bit-equals
// (double)i_f for i_f in [0,23] (R5-verified). Field bounds: qx,qy in
// [0,1035] (11 bits), i,j in [0,23] (5 bits); 5|5|11|11 pack is
// lexicographic in (j,i,qy,qx) == reference decimal-code order. Max code
// <= 0xBDE05C0B so code+1 never wraps and 0xFFFFFFFF is a safe sentinel.
__device__ __forceinline__ unsigned int hslot(unsigned int code) {
    return (code * 2654435761u) >> 18;   // top 14 bits -> [0, TBL)
}

// D1: codes + epoch-tagged claim + hardware atomicMax winner key +
// compact/slot emit. 32 blocks x 256 = one thread per element.
__global__ void __launch_bounds__(256)
k_insert(const float4* __restrict__ rects, const float* __restrict__ conf,
         unsigned long long* __restrict__ v64,
         unsigned int* __restrict__ compact,
         unsigned int* __restrict__ slot) {
    __shared__ unsigned int s_E;
    const int t = threadIdx.x;
    if (t == 0) {
        unsigned int tk = atomicAdd(&g_ctr, 1u);
        unsigned int E  = (tk >> 5) + 1u;       // tk / D1B + 1
        s_E  = E;
        g_cur = E;                               // benign same-value race
    }
    const int lane = t & 63;
    float powL = (float)pow((double)1.2f, (double)(float)lane);  // R5-verified LUT
    __syncthreads();
    const unsigned int E = s_E;

    const int i = blockIdx.x * 256 + t;
    float4 r = rects[i];
    const float LOG_ALPHA = (float)log((double)1.2f);
    const float LOGW0     = (float)log(512.0);
    float i_f = rintf((LOGW0 - (float)log((double)r.z)) / LOG_ALPHA);
    float j_f = rintf((LOGW0 - (float)log((double)r.w)) / LOG_ALPHA);
    float pi  = __shfl(powL, (int)i_f);
    float pj  = __shfl(powL, (int)j_f);
    float qx  = rintf(r.x / (128.0f / pi) - 0.5f);
    float qy  = rintf(r.y / (128.0f / pj) - 0.5f);
    unsigned int code = (unsigned int)qx | ((unsigned int)qy << 11)
                      | ((unsigned int)i_f << 22) | ((unsigned int)j_f << 27);
    unsigned int cb = __float_as_uint(conf[i]);
    v64[i] = ((unsigned long long)code << 32) | cb;

    // epoch-tagged claim (R8-verified): replace stale content via CAS;
    // advance past other-code current-epoch slots. Claims only grow within
    // an epoch -> exactly one claimer per distinct code, and ALL members
    // of a duplicate group converge to the same final slot h (monotone
    // slot states + same linear probe order).
    unsigned long long want = ((unsigned long long)E << 32) | (code + 1u);
    unsigned int h = hslot(code);
    bool claimed = false;
    for (;;) {
        unsigned long long cur = __hip_atomic_load(&g_tbl[h], __ATOMIC_RELAXED,
                                                   __HIP_MEMORY_SCOPE_AGENT);
        if (cur == want) break;                        // claimed by a racer
        if ((unsigned int)(cur >> 32) == E) {          // other code, this epoch
            h = (h + 1) & TBLM;
            continue;
        }
        unsigned long long prev = atomicCAS(&g_tbl[h], cur, want);
        if (prev == cur)  { claimed = true; break; }
        if (prev == want) break;                       // same-code racer won
        // else: slot changed under us -> re-inspect same slot
    }
    compact[i] = claimed ? code : 0xFFFFFFFFu;
    slot[i]    = h;

    // winner key: ONE hardware atomicMax. Epoch in top bits supersedes all
    // stale epochs; within this epoch: max conf (30-bit), tie -> smaller
    // index (larger 8191-i) — the R4-verified reference argmax order.
    atomicMax(&g_tkey[h], ((unsigned long long)E << 43)
                        | ((unsigned long long)cb << 13)
                        | (unsigned int)(8191 - i));
}

// D2: register-tiled rank + scatter + tail-zero (R7-verified structure).
// 256 blocks x 512; block owns 32 i's. rank_i = #{distinct codes < ci}
// (sentinels never count; self not < self). Winner check is a single
// load g_tkey[slot[i]] — no table probe.
__global__ void __launch_bounds__(512)
k_rank(const unsigned long long* __restrict__ v64,
       const unsigned int* __restrict__ compact,
       const unsigned int* __restrict__ slot,
       int* __restrict__ out) {
    __shared__ unsigned int s_ci[32];
    __shared__ int s_part[8][32];        // [wave][i_local]
    __shared__ int s_u[2];
    const int t = threadIdx.x;
    const int b = blockIdx.x;
    if (t < 32) s_ci[t] = (unsigned int)(v64[b * 32 + t] >> 32);
    __syncthreads();

    const int g    = t >> 7;             // 4 groups x 128 threads (2 waves)
    const int lt   = t & 127;
    const int wave = t >> 6;             // 0..7; group = wave>>1

    unsigned int ci[8];
    #pragma unroll
    for (int q = 0; q < 8; ++q)
        ci[q] = __builtin_amdgcn_readfirstlane(s_ci[g * 8 + q]);

    int r[8] = {0, 0, 0, 0, 0, 0, 0, 0};
    int u = 0;
    const uint4* c4 = (const uint4*)compact;   // 2048 uint4 = 8192 entries
    #pragma unroll
    for (int k = 0; k < 16; ++k) {
        uint4 e = c4[lt + k * 128];
        u += (int)(e.x != 0xFFFFFFFFu) + (int)(e.y != 0xFFFFFFFFu)
           + (int)(e.z != 0xFFFFFFFFu) + (int)(e.w != 0xFFFFFFFFu);
        #pragma unroll
        for (int q = 0; q < 8; ++q) {
            r[q] += (int)(e.x < ci[q]) + (int)(e.y < ci[q])
                  + (int)(e.z < ci[q]) + (int)(e.w < ci[q]);
        }
    }
    #pragma unroll
    for (int q = 0; q < 8; ++q) {
        r[q] += __shfl_xor(r[q], 1);
        r[q] += __shfl_xor(r[q], 2);
        r[q] += __shfl_xor(r[q], 4);
        r[q] += __shfl_xor(r[q], 8);
        r[q] += __shfl_xor(r[q], 16);
        r[q] += __shfl_xor(r[q], 32);
    }
    u += __shfl_xor(u, 1);  u += __shfl_xor(u, 2);  u += __shfl_xor(u, 4);
    u += __shfl_xor(u, 8);  u += __shfl_xor(u, 16); u += __shfl_xor(u, 32);
    if ((t & 63) == 0) {
        #pragma unroll
        for (int q = 0; q < 8; ++q)
            s_part[wave][(wave >> 1) * 8 + q] = r[q];
        if (wave < 2) s_u[wave] = u;     // group 0's two waves cover all 2048
    }
    __syncthreads();

    if (t < 32) {
        const int U  = s_u[0] + s_u[1];
        const int i  = b * 32 + t;
        const int gg = t >> 3;
        const int rr = s_part[2 * gg][t] + s_part[2 * gg + 1][t];

        unsigned long long vi = v64[i];
        unsigned long long wk = g_tkey[slot[i]];
        unsigned int E = g_cur;
        bool iswin = ((unsigned int)(wk >> 43) == E)
                  && (((unsigned int)wk & 0x1FFFu) == (unsigned int)(8191 - i));
        if (iswin)
            out[rr] = ((unsigned int)vi == 0u) ? 0 : i;  // all-conf-0 group -> 0
        if (i >= U)
            out[i] = 0;     // reference pads unique with fill -> argmax 0
    }
}

extern "C" void kernel_launch(void* const* d_in, const int* in_sizes, int n_in,
                              void* d_out, int out_size, void* d_ws, size_t ws_size,
                              hipStream_t stream) {
    const float4* rects = (const float4*)d_in[0];   // (8192, 4) f32
    const float*  conf  = (const float*)d_in[1];    // (8192,)  f32
    int* out = (int*)d_out;                         // int32 indices

    char* ws = (char*)d_ws;
    unsigned long long* v64     = (unsigned long long*)ws;        // 64 KiB
    unsigned int*       compact = (unsigned int*)(ws + 65536);    // 32 KiB
    unsigned int*       slot    = (unsigned int*)(ws + 98304);    // 32 KiB

    k_insert<<<D1B, 256, 0, stream>>>(rects, conf, v64, compact, slot);
    k_rank  <<<256, 512, 0, stream>>>(v64, compact, slot, out);
}

// Round 11
// 72.292 us; speedup vs baseline: 1.0935x; 1.0523x over previous
//
#include <hip/hip_runtime.h>
#include <math.h>

#define N    8192
#define TBL  16384           // hash slots = 2x N, load factor <= 0.5
#define TBLM 16383

// Structure: R7's 3-dispatch pipeline (measured best, 73.2 µs) with three
// verified micro-cuts: shfl-pow LUT in k_init (R5/R8-R10-verified
// bit-identical), slot[] side-channel killing k_rank's probe loop
// (R10-verified), and removal of k_init's redundant out-zeroing (winner
// ranks biject onto [0,U); k_rank tail-zeroes [U,N)).
//
// Cross-round accounting (R0-R10): timed dur = ~39.5 µs harness ws-poison
// fill (85% HBM peak) + ~25-35 µs harness restore-dispatch storm (fill
// _ord spacing 28-60/iter) + our ~8-11 µs. Grid-wide in-kernel sync is
// catastrophic on 8 XCDs (R2: 85 µs/sync; R3: 240 µs; R4: 84 µs) — only
// dispatch boundaries synchronize cheaply.
//
// Verified math (absmax 0.0, R1-R10): i = rint((log512 - log w)/log 1.2)
// [f32 ops, (double) log], di = 128/1.2^i, qx = rint(x/di - 0.5); pow via
// 64-lane shfl LUT ((double)(float)lane bit-equals (double)i_f, i_f in
// [0,23]). Field bounds: qx,qy in [0,1035] (11b), i,j in [0,23] (5b);
// 5|5|11|11 pack is lexicographic in (j,i,qy,qx) == reference decimal-
// code order. Max code <= 0xBDE05C0B: code+1 never wraps, 0xFFFFFFFF is
// a safe pad sentinel.
__device__ __forceinline__ unsigned int hslot(unsigned int code) {
    return (code * 2654435761u) >> 18;   // top 14 bits -> [0, TBL)
}

// D1: zero table/cnt + codes (LUT pow) + pad compact. Plain stores only.
// 64 blocks x 256 = 16384 threads.
__global__ void __launch_bounds__(256)
k_init(const float4* __restrict__ rects, const float* __restrict__ conf,
       unsigned long long* __restrict__ v64,
       unsigned int* __restrict__ tcode, unsigned long long* __restrict__ tkey,
       unsigned int* __restrict__ compact, unsigned int* __restrict__ cnt) {
    const int t  = threadIdx.x;
    const int gt = blockIdx.x * 256 + t;        // 0..16383
    tcode[gt] = 0u;            // empty = 0 (codes stored as code+1)
    tkey[gt]  = 0ULL;
    if (gt < N) {
        const int lane = t & 63;
        float powL = (float)pow((double)1.2f, (double)(float)lane);
        float4 r = rects[gt];
        const float LOG_ALPHA = (float)log((double)1.2f);
        const float LOGW0     = (float)log(512.0);
        float i_f = rintf((LOGW0 - (float)log((double)r.z)) / LOG_ALPHA);
        float j_f = rintf((LOGW0 - (float)log((double)r.w)) / LOG_ALPHA);
        float pi  = __shfl(powL, (int)i_f);
        float pj  = __shfl(powL, (int)j_f);
        float qx  = rintf(r.x / (128.0f / pi) - 0.5f);
        float qy  = rintf(r.y / (128.0f / pj) - 0.5f);
        unsigned int code = (unsigned int)qx | ((unsigned int)qy << 11)
                          | ((unsigned int)i_f << 22) | ((unsigned int)j_f << 27);
        v64[gt] = ((unsigned long long)code << 32)
                | (unsigned long long)__float_as_uint(conf[gt]);
        compact[gt] = 0xFFFFFFFFu;  // pad: > any real code, never counted
    }
    if (gt == 0) *cnt = 0u;
}

// D2: hash insert (R7-verified) + slot record. 128 blocks x 64 (1 wave).
// Claim slot by CAS; group-argmax via 64-bit atomicMax of
// (conf_bits<<32 | N-1-i): max conf, tie -> smaller index — exactly the
// reference argmax order. Claimers append their distinct code to
// compact[] with ONE wave-aggregated atomicAdd. All members of a
// duplicate group converge to the same slot h (grow-only claims + same
// linear probe order) -> slot[i] is group-consistent.
__global__ void __launch_bounds__(64)
k_insert(const unsigned long long* __restrict__ v64,
         unsigned int* __restrict__ tcode,
         unsigned long long* __restrict__ tkey,
         unsigned int* __restrict__ compact,
         unsigned int* __restrict__ cnt,
         unsigned int* __restrict__ slot) {
    int i = blockIdx.x * 64 + threadIdx.x;
    int lane = threadIdx.x;
    unsigned long long v = v64[i];
    unsigned int code = (unsigned int)(v >> 32);
    unsigned int tag  = code + 1u;
    unsigned int h = hslot(code);
    bool claimed = false;
    for (;;) {
        unsigned int prev = atomicCAS(&tcode[h], 0u, tag);
        if (prev == 0u) { claimed = true; break; }
        if (prev == tag) break;
        h = (h + 1) & TBLM;
    }
    slot[i] = h;
    atomicMax(&tkey[h], (v << 32) | (unsigned int)(N - 1 - i));
    unsigned long long mask = __ballot(claimed);
    if (mask) {
        int leader = __ffsll((long long)mask) - 1;
        unsigned int base = 0;
        if (lane == leader)
            base = atomicAdd(cnt, (unsigned int)__popcll(mask));
        base = (unsigned int)__shfl((int)base, leader);
        if (claimed) {
            unsigned int off = (unsigned int)__popcll(
                mask & ((1ULL << lane) - 1ULL));
            compact[base + off] = code;
        }
    }
}

// D3: register-tiled rank + scatter + tail-zero (R7-verified). 256 blocks
// x 512; block owns 32 i's. rank_i = #{distinct codes < ci} (pad never
// counts; self not < self). Winner check is one load tkey[slot[i]].
// out coverage: winners biject onto [0,U); tail-zero covers [U,N).
__global__ void __launch_bounds__(512)
k_rank(const unsigned long long* __restrict__ v64,
       const unsigned long long* __restrict__ tkey,
       const unsigned int* __restrict__ compact,
       const unsigned int* __restrict__ slot,
       int* __restrict__ out) {
    __shared__ unsigned int s_ci[32];
    __shared__ int s_part[8][32];        // [wave][i_local]
    __shared__ int s_u[2];
    const int t = threadIdx.x;
    const int b = blockIdx.x;
    if (t < 32) s_ci[t] = (unsigned int)(v64[b * 32 + t] >> 32);
    __syncthreads();

    const int g    = t >> 7;             // 4 groups x 128 threads (2 waves)
    const int lt   = t & 127;
    const int wave = t >> 6;             // 0..7; group = wave>>1

    unsigned int ci[8];
    #pragma unroll
    for (int q = 0; q < 8; ++q)
        ci[q] = __builtin_amdgcn_readfirstlane(s_ci[g * 8 + q]);

    int r[8] = {0, 0, 0, 0, 0, 0, 0, 0};
    int u = 0;
    const uint4* c4 = (const uint4*)compact;   // 2048 uint4 = 8192 entries
    #pragma unroll
    for (int k = 0; k < 16; ++k) {
        uint4 e = c4[lt + k * 128];
        u += (int)(e.x != 0xFFFFFFFFu) + (int)(e.y != 0xFFFFFFFFu)
           + (int)(e.z != 0xFFFFFFFFu) + (int)(e.w != 0xFFFFFFFFu);
        #pragma unroll
        for (int q = 0; q < 8; ++q) {
            r[q] += (int)(e.x < ci[q]) + (int)(e.y < ci[q])
                  + (int)(e.z < ci[q]) + (int)(e.w < ci[q]);
        }
    }
    #pragma unroll
    for (int q = 0; q < 8; ++q) {
        r[q] += __shfl_xor(r[q], 1);
        r[q] += __shfl_xor(r[q], 2);
        r[q] += __shfl_xor(r[q], 4);
        r[q] += __shfl_xor(r[q], 8);
        r[q] += __shfl_xor(r[q], 16);
        r[q] += __shfl_xor(r[q], 32);
    }
    u += __shfl_xor(u, 1);  u += __shfl_xor(u, 2);  u += __shfl_xor(u, 4);
    u += __shfl_xor(u, 8);  u += __shfl_xor(u, 16); u += __shfl_xor(u, 32);
    if ((t & 63) == 0) {
        #pragma unroll
        for (int q = 0; q < 8; ++q)
            s_part[wave][(wave >> 1) * 8 + q] = r[q];
        if (wave < 2) s_u[wave] = u;     // group 0's two waves cover all 2048
    }
    __syncthreads();

    if (t < 32) {
        const int U  = s_u[0] + s_u[1];
        const int i  = b * 32 + t;
        const int gg = t >> 3;
        const int rr = s_part[2 * gg][t] + s_part[2 * gg + 1][t];

        unsigned long long vi = v64[i];
        unsigned long long wk = tkey[slot[i]];   // one load, no probe
        if ((unsigned int)wk == (unsigned int)(N - 1 - i)) {
            // conf==0 winner => whole group conf 0 => all-zero score
            // column => reference argmax returns 0.
            out[rr] = ((unsigned int)vi == 0u) ? 0 : i;
        }
        if (i >= U)
            out[i] = 0;     // reference pads unique with fill -> argmax 0
    }
}

extern "C" void kernel_launch(void* const* d_in, const int* in_sizes, int n_in,
                              void* d_out, int out_size, void* d_ws, size_t ws_size,
                              hipStream_t stream) {
    const float4* rects = (const float4*)d_in[0];   // (8192, 4) f32
    const float*  conf  = (const float*)d_in[1];    // (8192,)  f32
    int* out = (int*)d_out;                         // int32 indices

    char* ws = (char*)d_ws;
    unsigned long long* v64     = (unsigned long long*)ws;             // 64 KiB
    unsigned int*       tcode   = (unsigned int*)(ws + 65536);         // 64 KiB
    unsigned long long* tkey    = (unsigned long long*)(ws + 131072);  // 128 KiB
    unsigned int*       compact = (unsigned int*)(ws + 262144);        // 32 KiB
    unsigned int*       slot    = (unsigned int*)(ws + 294912);        // 32 KiB
    unsigned int*       cnt     = (unsigned int*)(ws + 327680);        // 4 B

    k_init  <<<TBL / 256, 256, 0, stream>>>(rects, conf, v64, tcode, tkey,
                                            compact, cnt);
    k_insert<<<N / 64, 64, 0, stream>>>(v64, tcode, tkey, compact, cnt, slot);
    k_rank  <<<256, 512, 0, stream>>>(v64, tkey, compact, slot, out);
}